// Round 1
// baseline (774.778 us; speedup 1.0000x reference)
//
#include <hip/hip_runtime.h>
#include <stdint.h>

// VQ: z [32,256,32,32] f32, embedding [8192,256] f32.
// N = 32768 rows (n = b*1024 + h*32 + w), d = 256, K = 8192 codes.
// out = [ z_q (8388608 f32, [b,c,h,w]) | diff (1 f32) | idx (32768 f32) ]
//
// Strategy: fp16 Ootomo split GEMM (hi*hi + hi*lo + lo*hi, K' = 768) with
// mfma_f32_16x16x32_f16, fused row-argmin via packed u64 atomicMin.
// Workspace layout (bytes):
//   z_hi  [32768][256] f16 @ 0          (16777216)
//   z_lo                  @ 16777216    (16777216)
//   e_hi  [8192][256] f16 @ 33554432    (4194304)
//   e_lo                  @ 37748736    (4194304)
//   e_norm[8192] f32      @ 41943040    (32768)
//   table [32768] u64     @ 41975808    (262144)   total 42237952 B

typedef _Float16 half8 __attribute__((ext_vector_type(8)));
typedef float floatx4 __attribute__((ext_vector_type(4)));

#define BETA 0.25f

__device__ __forceinline__ void gl_lds16(const void* g, void* l) {
  __builtin_amdgcn_global_load_lds(
      (const __attribute__((address_space(1))) void*)g,
      (__attribute__((address_space(3))) void*)l, 16, 0, 0);
}

// ---------------- split z: [b,c,hw] f32 -> [n,c] f16 hi/lo (LDS transpose) --
__global__ __launch_bounds__(256) void split_z_t(const float* __restrict__ z,
                                                 _Float16* __restrict__ zh,
                                                 _Float16* __restrict__ zl) {
  __shared__ float tile[64][65];  // [c][hw], +1 pad
  int bt = blockIdx.x;       // 2048 blocks: 512 n-tiles x 4 c-tiles
  int ct = bt & 3;
  int ntile = bt >> 2;
  int b = ntile >> 4;        // 16 n-tiles of 64 per b (64 | 1024)
  int hw0 = (ntile & 15) * 64;
  int c0 = ct * 64;
  int t = threadIdx.x;
  int tr = t >> 6;           // 0..3
  int tc = t & 63;           // 0..63
#pragma unroll
  for (int i = 0; i < 16; ++i) {
    int c = tr + i * 4;
    tile[c][tc] = z[b * 262144 + (c0 + c) * 1024 + hw0 + tc];  // coalesced
  }
  __syncthreads();
#pragma unroll
  for (int i = 0; i < 16; ++i) {
    int nrow = tr + i * 4;
    float v = tile[tc][nrow];          // stride-65 -> conflict-free
    _Float16 hi = (_Float16)v;
    _Float16 lo = (_Float16)(v - (float)hi);
    int n = b * 1024 + hw0 + nrow;
    zh[n * 256 + c0 + tc] = hi;        // 128B contiguous per 64 lanes
    zl[n * 256 + c0 + tc] = lo;
  }
}

// ---------------- split e + ||e||^2 ---------------------------------------
__global__ __launch_bounds__(256) void split_e(const float* __restrict__ e,
                                               _Float16* __restrict__ eh,
                                               _Float16* __restrict__ el,
                                               float* __restrict__ en) {
  __shared__ float red[256];
  int k = blockIdx.x, c = threadIdx.x;
  float v = e[k * 256 + c];
  _Float16 hi = (_Float16)v;
  _Float16 lo = (_Float16)(v - (float)hi);
  eh[k * 256 + c] = hi;
  el[k * 256 + c] = lo;
  red[c] = v * v;
  __syncthreads();
  for (int s = 128; s > 0; s >>= 1) {
    if (c < s) red[c] += red[c + s];
    __syncthreads();
  }
  if (c == 0) en[k] = red[0];
}

// ---------------- main: split-fp16 GEMM + fused argmin --------------------
// grid (64 k-tiles, 256 n-tiles), block 256 = 4 waves (2x2 of 64x64).
__global__ __launch_bounds__(256) void vq_main(const _Float16* __restrict__ z_hi,
                                               const _Float16* __restrict__ z_lo,
                                               const _Float16* __restrict__ e_hi,
                                               const _Float16* __restrict__ e_lo,
                                               const float* __restrict__ e_norm,
                                               unsigned long long* __restrict__ table) {
  __shared__ __align__(16) _Float16 lA[128 * 64];  // [row][64], chunk-swizzled
  __shared__ __align__(16) _Float16 lB[128 * 64];
  const int tid = threadIdx.x;
  const int l = tid & 63;
  const int w = tid >> 6;
  const int wm = w >> 1, wn = w & 1;
  const int n0 = blockIdx.y * 128;
  const int k0 = blockIdx.x * 128;

  floatx4 acc[4][4] = {};

  const int srow = l >> 3;  // 8 rows per staging instr
  const int slot = l & 7;   // 8 chunks of 8 halves per row
  const int cl = l & 15;
  const int q = l >> 4;

  for (int it = 0; it < 12; ++it) {     // K' = 768, BK = 64
    const int p = it >> 2;              // pass: 0 hi*hi, 1 hi*lo, 2 lo*hi
    const int c0 = (it & 3) * 64;
    const _Float16* As = (p < 2) ? z_hi : z_lo;
    const _Float16* Bs = (p == 1) ? e_lo : e_hi;
#pragma unroll
    for (int i = 0; i < 4; ++i) {       // wave w stages rows [w*32, w*32+32)
      int row0 = w * 32 + i * 8;
      int row = row0 + srow;
      int chunk = slot ^ (row & 7);     // XOR swizzle (source side)
      gl_lds16(As + ((n0 + row) * 256 + c0 + chunk * 8), &lA[row0 * 64]);
      gl_lds16(Bs + ((k0 + row) * 256 + c0 + chunk * 8), &lB[row0 * 64]);
    }
    __syncthreads();                    // drains vmcnt before barrier
#pragma unroll
    for (int kk = 0; kk < 2; ++kk) {
      half8 af[4], bf[4];
#pragma unroll
      for (int im = 0; im < 4; ++im) {
        int m = wm * 64 + im * 16 + cl;
        int s = (kk * 4 + q) ^ (m & 7);
        af[im] = *(const half8*)&lA[m * 64 + s * 8];
      }
#pragma unroll
      for (int in = 0; in < 4; ++in) {
        int n = wn * 64 + in * 16 + cl;
        int s = (kk * 4 + q) ^ (n & 7);
        bf[in] = *(const half8*)&lB[n * 64 + s * 8];
      }
#pragma unroll
      for (int im = 0; im < 4; ++im)
#pragma unroll
        for (int in = 0; in < 4; ++in)
          acc[im][in] = __builtin_amdgcn_mfma_f32_16x16x32_f16(
              af[im], bf[in], acc[im][in], 0, 0, 0);
    }
    __syncthreads();
  }

  // Epilogue: d = ||e||^2 - 2*dot (||z||^2 is row-constant, irrelevant to argmin).
  // C/D layout: col = lane&15, row = (lane>>4)*4 + reg.
#pragma unroll
  for (int im = 0; im < 4; ++im) {
#pragma unroll
    for (int r = 0; r < 4; ++r) {
      int nrow = n0 + wm * 64 + im * 16 + q * 4 + r;
      float bd = 3.4e38f;
      unsigned bk = 0xffffffffu;
#pragma unroll
      for (int in = 0; in < 4; ++in) {
        unsigned k = (unsigned)(k0 + wn * 64 + in * 16 + cl);
        float d = e_norm[k] - 2.0f * acc[im][in][r];
        if (d < bd || (d == bd && k < bk)) { bd = d; bk = k; }
      }
      // reduce across the 16 lanes sharing q (cols of this row)
      for (int s = 1; s < 16; s <<= 1) {
        float od = __shfl_xor(bd, s);
        unsigned ok = __shfl_xor(bk, s);
        if (od < bd || (od == bd && ok < bk)) { bd = od; bk = ok; }
      }
      if (cl == 0) {
        unsigned u = __float_as_uint(bd);
        u = ((int)u >= 0) ? (u | 0x80000000u) : ~u;  // monotonic key
        unsigned long long packed =
            ((unsigned long long)u << 32) | (unsigned long long)bk;
        atomicMin(&table[nrow], packed);
      }
    }
  }
}

// ---------------- finalize: idx (as float) + diff -------------------------
__global__ __launch_bounds__(256) void finalize_idx_diff(
    const unsigned long long* __restrict__ table, const float* __restrict__ emb,
    const _Float16* __restrict__ zh, const _Float16* __restrict__ zl,
    float* __restrict__ out_idx, float* __restrict__ diff) {
  __shared__ float red[256];
  __shared__ unsigned kid[32];
  int t = threadIdx.x;
  int n0 = blockIdx.x * 32;
  if (t < 32) {
    unsigned k = (unsigned)table[n0 + t];  // low 32 bits = idx
    kid[t] = k;
    out_idx[n0 + t] = (float)k;
  }
  __syncthreads();
  float s = 0.f;
  for (int i = 0; i < 32; ++i) {
    int n = n0 + i;
    float e = emb[kid[i] * 256 + t];
    float zv = (float)zh[n * 256 + t] + (float)zl[n * 256 + t];
    float d = e - zv;
    s += d * d;
  }
  red[t] = s;
  __syncthreads();
  for (int st = 128; st > 0; st >>= 1) {
    if (t < st) red[t] += red[t + st];
    __syncthreads();
  }
  if (t == 0) atomicAdd(diff, red[0] * (BETA / 8388608.0f));
}

// ---------------- gather z_q into [b,c,h,w] -------------------------------
__global__ __launch_bounds__(256) void gather_zq(
    const unsigned long long* __restrict__ table, const float* __restrict__ emb,
    float* __restrict__ out) {
  int bx = blockIdx.x;  // 8192 = 32 b x 256 c
  int b = bx >> 8, c = bx & 255;
  int t = threadIdx.x;
  const unsigned* tl = (const unsigned*)table;
#pragma unroll
  for (int i = 0; i < 4; ++i) {
    int hw = i * 256 + t;
    int n = (b << 10) + hw;
    unsigned k = tl[2 * n];                      // LE low word = idx
    out[((b << 8) + c) * 1024 + hw] = emb[k * 256 + c];  // coalesced store
  }
}

extern "C" void kernel_launch(void* const* d_in, const int* in_sizes, int n_in,
                              void* d_out, int out_size, void* d_ws, size_t ws_size,
                              hipStream_t stream) {
  const float* z = (const float*)d_in[0];
  const float* emb = (const float*)d_in[1];
  char* ws = (char*)d_ws;
  _Float16* zh = (_Float16*)(ws);
  _Float16* zl = (_Float16*)(ws + 16777216);
  _Float16* eh = (_Float16*)(ws + 33554432);
  _Float16* el = (_Float16*)(ws + 37748736);
  float* en = (float*)(ws + 41943040);
  unsigned long long* table = (unsigned long long*)(ws + 41975808);

  float* out = (float*)d_out;
  float* out_zq = out;                 // 8388608
  float* out_diff = out + 8388608;     // 1
  float* out_idx = out + 8388609;      // 32768

  hipMemsetAsync(table, 0xFF, 32768ull * 8, stream);  // +inf keys
  hipMemsetAsync(out_diff, 0, 4, stream);

  split_z_t<<<2048, 256, 0, stream>>>(z, zh, zl);
  split_e<<<8192, 256, 0, stream>>>(emb, eh, el, en);
  vq_main<<<dim3(64, 256), 256, 0, stream>>>(zh, zl, eh, el, en, table);
  finalize_idx_diff<<<1024, 256, 0, stream>>>(table, emb, zh, zl, out_idx, out_diff);
  gather_zq<<<8192, 256, 0, stream>>>(table, emb, out_zq);
}

// Round 2
// 592.700 us; speedup vs baseline: 1.3072x; 1.3072x over previous
//
#include <hip/hip_runtime.h>
#include <stdint.h>

// VQ: z [32,256,32,32] f32, embedding [8192,256] f32.
// N = 32768 rows, d = 256, K = 8192 codes.
// out = [ z_q (8388608 f32, [b,c,h,w]) | diff (1 f32) | idx (32768 f32) ]
//
// R2: coarse fp16 hi*hi GEMM (K'=256) with per-lane running top-2 per row,
// per-(row, 1024-code block) top-2 emitted (no atomics), exact fp64 refine
// over 16 candidates/row picks the true argmin + diff. Gather as before.
//
// Workspace (bytes):
//   z_t   [32768][256] f32 @ 0          (33554432)   exact transposed z
//   z_hi  [32768][256] f16 @ 33554432   (16777216)
//   e_hi  [8192][256]  f16 @ 50331648   (4194304)
//   e_norm[8192]       f32 @ 54525952   (32768)
//   cand  [32768][16]  u32 @ 54558720   (2097152)
//   win   [32768]      u32 @ 56655872   (131072)    total 56786944

typedef _Float16 half8 __attribute__((ext_vector_type(8)));
typedef float floatx4 __attribute__((ext_vector_type(4)));

#define BETA 0.25f

__device__ __forceinline__ void gl_lds16(const void* g, void* l) {
  __builtin_amdgcn_global_load_lds(
      (const __attribute__((address_space(1))) void*)g,
      (__attribute__((address_space(3))) void*)l, 16, 0, 0);
}

// ---------------- split z: [b,c,hw] f32 -> [n,c] f32 + f16 hi --------------
__global__ __launch_bounds__(256) void split_z_t(const float* __restrict__ z,
                                                 float* __restrict__ zt,
                                                 _Float16* __restrict__ zh) {
  __shared__ float tile[64][65];  // [c][hw], +1 pad
  int bt = blockIdx.x;       // 2048 blocks: 512 n-tiles x 4 c-tiles
  int ct = bt & 3;
  int ntile = bt >> 2;
  int b = ntile >> 4;        // 16 n-tiles of 64 per b
  int hw0 = (ntile & 15) * 64;
  int c0 = ct * 64;
  int t = threadIdx.x;
  int tr = t >> 6;           // 0..3
  int tc = t & 63;           // 0..63
#pragma unroll
  for (int i = 0; i < 16; ++i) {
    int c = tr + i * 4;
    tile[c][tc] = z[b * 262144 + (c0 + c) * 1024 + hw0 + tc];  // coalesced
  }
  __syncthreads();
#pragma unroll
  for (int i = 0; i < 16; ++i) {
    int nrow = tr + i * 4;
    float v = tile[tc][nrow];          // stride-65 -> conflict-free
    int n = b * 1024 + hw0 + nrow;
    zt[n * 256 + c0 + tc] = v;
    zh[n * 256 + c0 + tc] = (_Float16)v;
  }
}

// ---------------- split e + ||e||^2 ---------------------------------------
__global__ __launch_bounds__(256) void split_e(const float* __restrict__ e,
                                               _Float16* __restrict__ eh,
                                               float* __restrict__ en) {
  __shared__ float red[256];
  int k = blockIdx.x, c = threadIdx.x;
  float v = e[k * 256 + c];
  eh[k * 256 + c] = (_Float16)v;
  red[c] = v * v;
  __syncthreads();
  for (int s = 128; s > 0; s >>= 1) {
    if (c < s) red[c] += red[c + s];
    __syncthreads();
  }
  if (c == 0) en[k] = red[0];
}

// ---------------- coarse GEMM + per-(row,block) top-2 ---------------------
// grid (8 code-groups of 1024, 256 n-tiles), block 256 = 4 waves (2x2 of 64).
__global__ __launch_bounds__(256) void vq_coarse(const _Float16* __restrict__ zh,
                                                 const _Float16* __restrict__ eh,
                                                 const float* __restrict__ en_,
                                                 unsigned* __restrict__ cand) {
  __shared__ __align__(16) _Float16 lA[128 * 64];
  __shared__ __align__(16) _Float16 lB[128 * 64];
  __shared__ unsigned long long ltop[128][2][2];  // [row][wn][2] = 4 KB
  const int tid = threadIdx.x;
  const int l = tid & 63;
  const int w = tid >> 6;
  const int wm = w >> 1, wn = w & 1;
  const int n0 = blockIdx.y * 128;
  const int kbase = blockIdx.x * 1024;
  const int srow = l >> 3;
  const int slot = l & 7;
  const int cl = l & 15;
  const int q = l >> 4;

  unsigned long long p1[16], p2[16];
#pragma unroll
  for (int s = 0; s < 16; ++s) { p1[s] = ~0ull; p2[s] = ~0ull; }

  for (int ct = 0; ct < 8; ++ct) {
    const int krow0 = kbase + ct * 128;
    floatx4 acc[4][4] = {};
#pragma unroll
    for (int it = 0; it < 4; ++it) {    // K' = 256, BK = 64
      const int c0 = it * 64;
#pragma unroll
      for (int i = 0; i < 4; ++i) {     // wave w stages rows [w*32, w*32+32)
        int row0 = w * 32 + i * 8;
        int row = row0 + srow;
        int chunk = slot ^ (row & 7);   // XOR swizzle (source side)
        gl_lds16(zh + ((size_t)(n0 + row) * 256 + c0 + chunk * 8), &lA[row0 * 64]);
        gl_lds16(eh + ((size_t)(krow0 + row) * 256 + c0 + chunk * 8), &lB[row0 * 64]);
      }
      __syncthreads();
#pragma unroll
      for (int kk = 0; kk < 2; ++kk) {
        half8 af[4], bf[4];
#pragma unroll
        for (int im = 0; im < 4; ++im) {
          int m = wm * 64 + im * 16 + cl;
          int s = (kk * 4 + q) ^ (m & 7);
          af[im] = *(const half8*)&lA[m * 64 + s * 8];
        }
#pragma unroll
        for (int in = 0; in < 4; ++in) {
          int n = wn * 64 + in * 16 + cl;
          int s = (kk * 4 + q) ^ (n & 7);
          bf[in] = *(const half8*)&lB[n * 64 + s * 8];
        }
#pragma unroll
        for (int im = 0; im < 4; ++im)
#pragma unroll
          for (int in = 0; in < 4; ++in)
            acc[im][in] = __builtin_amdgcn_mfma_f32_16x16x32_f16(
                af[im], bf[in], acc[im][in], 0, 0, 0);
      }
      __syncthreads();
    }
    // running top-2 update. C/D layout: col=lane&15, row=(lane>>4)*4+reg.
#pragma unroll
    for (int in = 0; in < 4; ++in) {
      unsigned k = (unsigned)(krow0 + wn * 64 + in * 16 + cl);
      float env = en_[k];
#pragma unroll
      for (int im = 0; im < 4; ++im) {
#pragma unroll
        for (int r = 0; r < 4; ++r) {
          float d = env - 2.0f * acc[im][in][r];
          unsigned u = __float_as_uint(d);
          u = ((int)u >= 0) ? (u | 0x80000000u) : ~u;  // monotonic key
          unsigned long long c =
              ((unsigned long long)u << 32) | (unsigned long long)k;
          int s = im * 4 + r;
          unsigned long long mn = c < p1[s] ? c : p1[s];
          unsigned long long mx = c < p1[s] ? p1[s] : c;
          p1[s] = mn;
          p2[s] = mx < p2[s] ? mx : p2[s];
        }
      }
    }
  }

  // merge across the 16 lanes of each row group, then across wn via LDS
#pragma unroll
  for (int s = 0; s < 16; ++s) {
    unsigned long long a1 = p1[s], a2 = p2[s];
#pragma unroll
    for (int t = 1; t < 16; t <<= 1) {
      unsigned long long b1 = __shfl_xor(a1, t);
      unsigned long long b2 = __shfl_xor(a2, t);
      unsigned long long m1 = a1 < b1 ? a1 : b1;
      unsigned long long M  = a1 < b1 ? b1 : a1;
      unsigned long long m2 = a2 < b2 ? a2 : b2;
      a1 = m1;
      a2 = M < m2 ? M : m2;
    }
    if (cl == 0) {
      int im = s >> 2, r = s & 3;
      int rowl = wm * 64 + im * 16 + q * 4 + r;
      ltop[rowl][wn][0] = a1;
      ltop[rowl][wn][1] = a2;
    }
  }
  __syncthreads();
  if (tid < 128) {
    unsigned long long a1 = ltop[tid][0][0], a2 = ltop[tid][0][1];
    unsigned long long b1 = ltop[tid][1][0], b2 = ltop[tid][1][1];
    unsigned long long m1 = a1 < b1 ? a1 : b1;
    unsigned long long M  = a1 < b1 ? b1 : a1;
    unsigned long long m2 = a2 < b2 ? a2 : b2;
    unsigned long long f2 = M < m2 ? M : m2;
    unsigned i1 = (unsigned)m1, i2 = (unsigned)f2;  // low 32 bits = code idx
    unsigned long long packed = ((unsigned long long)i2 << 32) | i1;
    *(unsigned long long*)&cand[(size_t)(n0 + tid) * 16 + blockIdx.x * 2] = packed;
  }
}

// ---------------- exact fp64 refine over 16 candidates/row + diff ---------
__global__ __launch_bounds__(256) void vq_refine(const unsigned* __restrict__ cand,
                                                 const float* __restrict__ emb,
                                                 const float* __restrict__ zt,
                                                 float* __restrict__ out_idx,
                                                 unsigned* __restrict__ win,
                                                 float* __restrict__ diff) {
  int t = threadIdx.x;
  int w = t >> 6, l = t & 63;
  double wsum = 0.0;
  for (int i = 0; i < 8; ++i) {
    int n = blockIdx.x * 32 + w * 8 + i;
    floatx4 zv = *(const floatx4*)&zt[(size_t)n * 256 + l * 4];
    unsigned ks[16];
    double s[16];
#pragma unroll
    for (int j = 0; j < 16; ++j) {
      unsigned k = cand[n * 16 + j];
      ks[j] = k;
      floatx4 ev = *(const floatx4*)&emb[(size_t)k * 256 + l * 4];
      double acc = 0.0;
#pragma unroll
      for (int x = 0; x < 4; ++x) {
        double dd = (double)ev[x] - (double)zv[x];
        acc += dd * dd;
      }
      s[j] = acc;
    }
#pragma unroll
    for (int j = 0; j < 16; ++j)
#pragma unroll
      for (int st = 1; st < 64; st <<= 1) s[j] += __shfl_xor(s[j], st);
    double bestd = 1e300;
    unsigned bestk = 0xffffffffu;
#pragma unroll
    for (int j = 0; j < 16; ++j) {
      if (s[j] < bestd || (s[j] == bestd && ks[j] < bestk)) {
        bestd = s[j];
        bestk = ks[j];
      }
    }
    if (l == 0) {
      out_idx[n] = (float)bestk;
      win[n] = bestk;
    }
    wsum += bestd;  // every lane has the reduced value; use wave 'l==0' below
  }
  __shared__ float dsh[4];
  if (l == 0) dsh[w] = (float)(wsum * ((double)BETA / 8388608.0));
  __syncthreads();
  if (t == 0) atomicAdd(diff, dsh[0] + dsh[1] + dsh[2] + dsh[3]);
}

// ---------------- gather z_q into [b,c,h,w] -------------------------------
__global__ __launch_bounds__(256) void gather_zq(const unsigned* __restrict__ win,
                                                 const float* __restrict__ emb,
                                                 float* __restrict__ out) {
  int bx = blockIdx.x;  // 8192 = 32 b x 256 c
  int b = bx >> 8, c = bx & 255;
  int t = threadIdx.x;
#pragma unroll
  for (int i = 0; i < 4; ++i) {
    int hw = i * 256 + t;
    int n = (b << 10) + hw;
    unsigned k = win[n];
    out[((b << 8) + c) * 1024 + hw] = emb[k * 256 + c];  // coalesced store
  }
}

extern "C" void kernel_launch(void* const* d_in, const int* in_sizes, int n_in,
                              void* d_out, int out_size, void* d_ws, size_t ws_size,
                              hipStream_t stream) {
  const float* z = (const float*)d_in[0];
  const float* emb = (const float*)d_in[1];
  char* ws = (char*)d_ws;
  float* zt = (float*)(ws);
  _Float16* zh = (_Float16*)(ws + 33554432);
  _Float16* eh = (_Float16*)(ws + 50331648);
  float* en = (float*)(ws + 54525952);
  unsigned* cand = (unsigned*)(ws + 54558720);
  unsigned* win = (unsigned*)(ws + 56655872);

  float* out = (float*)d_out;
  float* out_zq = out;               // 8388608
  float* out_diff = out + 8388608;   // 1
  float* out_idx = out + 8388609;    // 32768

  hipMemsetAsync(out_diff, 0, 4, stream);

  split_z_t<<<2048, 256, 0, stream>>>(z, zt, zh);
  split_e<<<8192, 256, 0, stream>>>(emb, eh, en);
  vq_coarse<<<dim3(8, 256), 256, 0, stream>>>(zh, eh, en, cand);
  vq_refine<<<1024, 256, 0, stream>>>(cand, emb, zt, out_idx, win, out_diff);
  gather_zq<<<8192, 256, 0, stream>>>(win, emb, out_zq);
}

// Round 3
// 464.299 us; speedup vs baseline: 1.6687x; 1.2765x over previous
//
#include <hip/hip_runtime.h>
#include <stdint.h>

// VQ: z [32,256,32,32] f32, embedding [8192,256] f32.
// N = 32768 rows, d = 256, K = 8192 codes.
// out = [ z_q (8388608 f32, [b,c,h,w]) | diff (1 f32) | idx (32768 f32) ]
//
// R3: coarse fp16 hi*hi GEMM (K'=256); per-(row, 1024-code block) top-2 via
// u32 packed keys (monotonic f32 bits, low 10 bits = idx-in-block); exact
// fp64 refine over 16 candidates/row. No atomics in the GEMM.
//
// Workspace (bytes):
//   z_t   [32768][256] f32 @ 0          (33554432)   exact transposed z
//   z_hi  [32768][256] f16 @ 33554432   (16777216)
//   e_hi  [8192][256]  f16 @ 50331648   (4194304)
//   e_norm[8192]       f32 @ 54525952   (32768)
//   cand  [32768][16]  u32 @ 54558720   (2097152)
//   win   [32768]      u32 @ 56655872   (131072)    total 56786944

typedef _Float16 half8 __attribute__((ext_vector_type(8)));
typedef float floatx4 __attribute__((ext_vector_type(4)));

#define BETA 0.25f

__device__ __forceinline__ void gl_lds16(const void* g, void* l) {
  __builtin_amdgcn_global_load_lds(
      (const __attribute__((address_space(1))) void*)g,
      (__attribute__((address_space(3))) void*)l, 16, 0, 0);
}

// ---------------- split z: [b,c,hw] f32 -> [n,c] f32 + f16 hi --------------
__global__ __launch_bounds__(256) void split_z_t(const float* __restrict__ z,
                                                 float* __restrict__ zt,
                                                 _Float16* __restrict__ zh) {
  __shared__ float tile[64][65];  // [c][hw], +1 pad
  int bt = blockIdx.x;       // 2048 blocks: 512 n-tiles x 4 c-tiles
  int ct = bt & 3;
  int ntile = bt >> 2;
  int b = ntile >> 4;        // 16 n-tiles of 64 per b
  int hw0 = (ntile & 15) * 64;
  int c0 = ct * 64;
  int t = threadIdx.x;
  int tr = t >> 6;           // 0..3
  int tc = t & 63;           // 0..63
#pragma unroll
  for (int i = 0; i < 16; ++i) {
    int c = tr + i * 4;
    tile[c][tc] = z[b * 262144 + (c0 + c) * 1024 + hw0 + tc];  // coalesced
  }
  __syncthreads();
#pragma unroll
  for (int i = 0; i < 16; ++i) {
    int nrow = tr + i * 4;
    float v = tile[tc][nrow];          // stride-65 -> conflict-free
    int n = b * 1024 + hw0 + nrow;
    zt[n * 256 + c0 + tc] = v;
    zh[n * 256 + c0 + tc] = (_Float16)v;
  }
}

// ---------------- split e + ||e||^2 ---------------------------------------
__global__ __launch_bounds__(256) void split_e(const float* __restrict__ e,
                                               _Float16* __restrict__ eh,
                                               float* __restrict__ en) {
  __shared__ float red[256];
  int k = blockIdx.x, c = threadIdx.x;
  float v = e[k * 256 + c];
  eh[k * 256 + c] = (_Float16)v;
  red[c] = v * v;
  __syncthreads();
  for (int s = 128; s > 0; s >>= 1) {
    if (c < s) red[c] += red[c + s];
    __syncthreads();
  }
  if (c == 0) en[k] = red[0];
}

// ---------------- coarse GEMM + per-(row,block) top-2 ---------------------
// grid (8 code-groups of 1024, 256 n-tiles), block 256 = 4 waves (2x2 of 64).
__global__ __launch_bounds__(256, 3) void vq_coarse(
    const _Float16* __restrict__ zh, const _Float16* __restrict__ eh,
    const float* __restrict__ en_, unsigned* __restrict__ cand) {
  __shared__ __align__(16) _Float16 lA[128 * 64];
  __shared__ __align__(16) _Float16 lB[128 * 64];
  __shared__ unsigned ltop[128][2][2];  // [row][wn][2] = 2 KB
  const int tid = threadIdx.x;
  const int l = tid & 63;
  const int w = tid >> 6;
  const int wm = w >> 1, wn = w & 1;
  const int n0 = blockIdx.y * 128;
  const int kbase = blockIdx.x * 1024;
  const int srow = l >> 3;
  const int slot = l & 7;
  const int cl = l & 15;
  const int q = l >> 4;

  unsigned p1[16], p2[16];
#pragma unroll
  for (int s = 0; s < 16; ++s) { p1[s] = 0xFFFFFFFFu; p2[s] = 0xFFFFFFFFu; }

  for (int ct = 0; ct < 8; ++ct) {
    const int krow0 = kbase + ct * 128;
    floatx4 acc[4][4] = {};
#pragma unroll
    for (int it = 0; it < 4; ++it) {    // K' = 256, BK = 64
      const int c0 = it * 64;
#pragma unroll
      for (int i = 0; i < 4; ++i) {     // wave w stages rows [w*32, w*32+32)
        int row0 = w * 32 + i * 8;
        int row = row0 + srow;
        int chunk = slot ^ (row & 7);   // XOR swizzle (source side)
        gl_lds16(zh + ((size_t)(n0 + row) * 256 + c0 + chunk * 8), &lA[row0 * 64]);
        gl_lds16(eh + ((size_t)(krow0 + row) * 256 + c0 + chunk * 8), &lB[row0 * 64]);
      }
      __syncthreads();
#pragma unroll
      for (int kk = 0; kk < 2; ++kk) {
        half8 af[4], bf[4];
#pragma unroll
        for (int im = 0; im < 4; ++im) {
          int m = wm * 64 + im * 16 + cl;
          int s = (kk * 4 + q) ^ (m & 7);
          af[im] = *(const half8*)&lA[m * 64 + s * 8];
        }
#pragma unroll
        for (int in = 0; in < 4; ++in) {
          int n = wn * 64 + in * 16 + cl;
          int s = (kk * 4 + q) ^ (n & 7);
          bf[in] = *(const half8*)&lB[n * 64 + s * 8];
        }
#pragma unroll
        for (int im = 0; im < 4; ++im)
#pragma unroll
          for (int in = 0; in < 4; ++in)
            acc[im][in] = __builtin_amdgcn_mfma_f32_16x16x32_f16(
                af[im], bf[in], acc[im][in], 0, 0, 0);
      }
      __syncthreads();
    }
    // top-2 update with u32 packed keys.
    // C/D layout: col=lane&15, row=(lane>>4)*4+reg.
#pragma unroll
    for (int in = 0; in < 4; ++in) {
      unsigned loc = (unsigned)(ct * 128 + wn * 64 + in * 16 + cl);  // 0..1023
      float env = en_[kbase + loc];
#pragma unroll
      for (int im = 0; im < 4; ++im) {
#pragma unroll
        for (int r = 0; r < 4; ++r) {
          float d = fmaf(-2.0f, acc[im][in][r], env);
          unsigned u = __float_as_uint(d);
          u ^= ((unsigned)((int)u >> 31)) | 0x80000000u;  // monotonic
          unsigned c = (u & 0xFFFFFC00u) | loc;           // key | idx10
          int s = im * 4 + r;
          unsigned mn = min(p1[s], c);
          unsigned mx = max(p1[s], c);
          p1[s] = mn;
          p2[s] = min(p2[s], mx);
        }
      }
    }
  }

  // merge across the 16 lanes of each row group, then across wn via LDS
#pragma unroll
  for (int s = 0; s < 16; ++s) {
    unsigned a1 = p1[s], a2 = p2[s];
#pragma unroll
    for (int t = 1; t < 16; t <<= 1) {
      unsigned b1 = __shfl_xor(a1, t);
      unsigned b2 = __shfl_xor(a2, t);
      unsigned m1 = min(a1, b1);
      unsigned M = max(a1, b1);
      a1 = m1;
      a2 = min(min(a2, b2), M);
    }
    if (cl == 0) {
      int im = s >> 2, r = s & 3;
      int rowl = wm * 64 + im * 16 + q * 4 + r;
      ltop[rowl][wn][0] = a1;
      ltop[rowl][wn][1] = a2;
    }
  }
  __syncthreads();
  if (tid < 128) {
    unsigned a1 = ltop[tid][0][0], a2 = ltop[tid][0][1];
    unsigned b1 = ltop[tid][1][0], b2 = ltop[tid][1][1];
    unsigned m1 = min(a1, b1);
    unsigned M = max(a1, b1);
    unsigned f2 = min(min(a2, b2), M);
    unsigned long long packed = ((unsigned long long)f2 << 32) | m1;
    *(unsigned long long*)&cand[(size_t)(n0 + tid) * 16 + blockIdx.x * 2] = packed;
  }
}

// ---------------- exact fp64 refine over 16 candidates/row + diff ---------
__global__ __launch_bounds__(256) void vq_refine(const unsigned* __restrict__ cand,
                                                 const float* __restrict__ emb,
                                                 const float* __restrict__ zt,
                                                 float* __restrict__ out_idx,
                                                 unsigned* __restrict__ win,
                                                 float* __restrict__ diff) {
  int t = threadIdx.x;
  int w = t >> 6, l = t & 63;
  double wsum = 0.0;
  for (int i = 0; i < 8; ++i) {
    int n = blockIdx.x * 32 + w * 8 + i;
    floatx4 zv = *(const floatx4*)&zt[(size_t)n * 256 + l * 4];
    unsigned ks[16];
    double s[16];
#pragma unroll
    for (int j = 0; j < 16; ++j) {
      unsigned cv = cand[n * 16 + j];
      unsigned k = (unsigned)(j >> 1) * 1024 + (cv & 1023);
      ks[j] = k;
      floatx4 ev = *(const floatx4*)&emb[(size_t)k * 256 + l * 4];
      double acc = 0.0;
#pragma unroll
      for (int x = 0; x < 4; ++x) {
        double dd = (double)ev[x] - (double)zv[x];
        acc += dd * dd;
      }
      s[j] = acc;
    }
#pragma unroll
    for (int j = 0; j < 16; ++j)
#pragma unroll
      for (int st = 1; st < 64; st <<= 1) s[j] += __shfl_xor(s[j], st);
    double bestd = 1e300;
    unsigned bestk = 0xffffffffu;
#pragma unroll
    for (int j = 0; j < 16; ++j) {
      if (s[j] < bestd || (s[j] == bestd && ks[j] < bestk)) {
        bestd = s[j];
        bestk = ks[j];
      }
    }
    if (l == 0) {
      out_idx[n] = (float)bestk;
      win[n] = bestk;
    }
    wsum += bestd;
  }
  __shared__ float dsh[4];
  if (l == 0) dsh[w] = (float)(wsum * ((double)BETA / 8388608.0));
  __syncthreads();
  if (t == 0) atomicAdd(diff, dsh[0] + dsh[1] + dsh[2] + dsh[3]);
}

// ---------------- gather z_q into [b,c,h,w] -------------------------------
__global__ __launch_bounds__(256) void gather_zq(const unsigned* __restrict__ win,
                                                 const float* __restrict__ emb,
                                                 float* __restrict__ out) {
  int bx = blockIdx.x;  // 8192 = 32 b x 256 c
  int b = bx >> 8, c = bx & 255;
  int t = threadIdx.x;
#pragma unroll
  for (int i = 0; i < 4; ++i) {
    int hw = i * 256 + t;
    int n = (b << 10) + hw;
    unsigned k = win[n];
    out[((b << 8) + c) * 1024 + hw] = emb[k * 256 + c];  // coalesced store
  }
}

extern "C" void kernel_launch(void* const* d_in, const int* in_sizes, int n_in,
                              void* d_out, int out_size, void* d_ws, size_t ws_size,
                              hipStream_t stream) {
  const float* z = (const float*)d_in[0];
  const float* emb = (const float*)d_in[1];
  char* ws = (char*)d_ws;
  float* zt = (float*)(ws);
  _Float16* zh = (_Float16*)(ws + 33554432);
  _Float16* eh = (_Float16*)(ws + 50331648);
  float* en = (float*)(ws + 54525952);
  unsigned* cand = (unsigned*)(ws + 54558720);
  unsigned* win = (unsigned*)(ws + 56655872);

  float* out = (float*)d_out;
  float* out_zq = out;               // 8388608
  float* out_diff = out + 8388608;   // 1
  float* out_idx = out + 8388609;    // 32768

  hipMemsetAsync(out_diff, 0, 4, stream);

  split_z_t<<<2048, 256, 0, stream>>>(z, zt, zh);
  split_e<<<8192, 256, 0, stream>>>(emb, eh, en);
  vq_coarse<<<dim3(8, 256), 256, 0, stream>>>(zh, eh, en, cand);
  vq_refine<<<1024, 256, 0, stream>>>(cand, emb, zt, out_idx, win, out_diff);
  gather_zq<<<8192, 256, 0, stream>>>(win, emb, out_zq);
}

// Round 4
// 460.707 us; speedup vs baseline: 1.6817x; 1.0078x over previous
//
#include <hip/hip_runtime.h>
#include <stdint.h>

// VQ: z [32,256,32,32] f32, embedding [8192,256] f32.
// N = 32768 rows, d = 256, K = 8192 codes.
// out = [ z_q (8388608 f32, [b,c,h,w]) | diff (1 f32) | idx (32768 f32) ]
//
// R4: register-resident A (64 rows x 256 K per wave = 128 VGPR), B streamed
// L2->VGPR in MFMA layout, NO LDS staging / no K-loop barriers. Top-2 per
// (row, 1024-code group) with u32 keys (positive-float bits | idx10).
// Exact fp64 refine over 16 candidates/row. Same pre/post kernels as R3.
//
// Workspace (bytes):
//   z_t   [32768][256] f32 @ 0          (33554432)   exact transposed z
//   z_hi  [32768][256] f16 @ 33554432   (16777216)
//   e_hi  [8192][256]  f16 @ 50331648   (4194304)
//   e_norm[8192]       f32 @ 54525952   (32768)
//   cand  [32768][16]  u32 @ 54558720   (2097152)
//   win   [32768]      u32 @ 56655872   (131072)    total 56786944

typedef _Float16 half8 __attribute__((ext_vector_type(8)));
typedef float floatx4 __attribute__((ext_vector_type(4)));

#define BETA 0.25f

// ---------------- split z: [b,c,hw] f32 -> [n,c] f32 + f16 hi --------------
__global__ __launch_bounds__(256) void split_z_t(const float* __restrict__ z,
                                                 float* __restrict__ zt,
                                                 _Float16* __restrict__ zh) {
  __shared__ float tile[64][65];  // [c][hw], +1 pad
  int bt = blockIdx.x;       // 2048 blocks: 512 n-tiles x 4 c-tiles
  int ct = bt & 3;
  int ntile = bt >> 2;
  int b = ntile >> 4;        // 16 n-tiles of 64 per b
  int hw0 = (ntile & 15) * 64;
  int c0 = ct * 64;
  int t = threadIdx.x;
  int tr = t >> 6;           // 0..3
  int tc = t & 63;           // 0..63
#pragma unroll
  for (int i = 0; i < 16; ++i) {
    int c = tr + i * 4;
    tile[c][tc] = z[b * 262144 + (c0 + c) * 1024 + hw0 + tc];  // coalesced
  }
  __syncthreads();
#pragma unroll
  for (int i = 0; i < 16; ++i) {
    int nrow = tr + i * 4;
    float v = tile[tc][nrow];          // stride-65 -> conflict-free
    int n = b * 1024 + hw0 + nrow;
    zt[n * 256 + c0 + tc] = v;
    zh[n * 256 + c0 + tc] = (_Float16)v;
  }
}

// ---------------- split e + ||e||^2 ---------------------------------------
__global__ __launch_bounds__(256) void split_e(const float* __restrict__ e,
                                               _Float16* __restrict__ eh,
                                               float* __restrict__ en) {
  __shared__ float red[256];
  int k = blockIdx.x, c = threadIdx.x;
  float v = e[k * 256 + c];
  eh[k * 256 + c] = (_Float16)v;
  red[c] = v * v;
  __syncthreads();
  for (int s = 128; s > 0; s >>= 1) {
    if (c < s) red[c] += red[c + s];
    __syncthreads();
  }
  if (c == 0) en[k] = red[0];
}

// ---------------- coarse GEMM, A in registers, B streamed -----------------
// grid (4 kgroups of 2048, 256 n-tiles), block 256 = 4 waves.
// wave tile: 64 rows (wm half) x 32 codes (wn*32 + in*16 halves) per ct.
__global__ __launch_bounds__(256, 2) void vq_coarse(
    const _Float16* __restrict__ zh, const _Float16* __restrict__ eh,
    const float* __restrict__ en_, unsigned* __restrict__ cand) {
  __shared__ unsigned ltop[128][2][2];  // [row][wn][2] = 2 KB
  const int tid = threadIdx.x;
  const int l = tid & 63;
  const int w = tid >> 6;
  const int wm = w >> 1, wn = w & 1;
  const int n0 = blockIdx.y * 128;
  const int kbase = blockIdx.x * 2048;
  const int cl = l & 15;
  const int q = l >> 4;

  // A resident: rows n0 + wm*64 + im*16 + cl, cols it*64 + (kk*4+q)*8 + 0..7
  half8 A[4][2][4];  // [it][kk][im] = 32 half8 = 128 VGPR
#pragma unroll
  for (int it = 0; it < 4; ++it)
#pragma unroll
    for (int kk = 0; kk < 2; ++kk)
#pragma unroll
      for (int im = 0; im < 4; ++im)
        A[it][kk][im] = *(const half8*)&zh[(size_t)(n0 + wm * 64 + im * 16 + cl) * 256 +
                                           it * 64 + (kk * 4 + q) * 8];

  unsigned p1[16], p2[16];
#pragma unroll
  for (int s = 0; s < 16; ++s) { p1[s] = 0xFFFFFFFFu; p2[s] = 0xFFFFFFFFu; }

  for (int ct = 0; ct < 32; ++ct) {   // 2048 codes, 64 per ct
    const int krow0 = kbase + ct * 64;
    floatx4 acc[4][2] = {};  // [im][in]
#pragma unroll
    for (int it = 0; it < 4; ++it) {
#pragma unroll
      for (int kk = 0; kk < 2; ++kk) {
        half8 bf[2];
#pragma unroll
        for (int in = 0; in < 2; ++in)
          bf[in] = *(const half8*)&eh[(size_t)(krow0 + wn * 32 + in * 16 + cl) * 256 +
                                      it * 64 + (kk * 4 + q) * 8];
#pragma unroll
        for (int im = 0; im < 4; ++im)
#pragma unroll
          for (int in = 0; in < 2; ++in)
            acc[im][in] = __builtin_amdgcn_mfma_f32_16x16x32_f16(
                A[it][kk][im], bf[in], acc[im][in], 0, 0, 0);
      }
    }
    // top-2 update: d = ||e||^2 - 2*dot > 0 always on this data, so
    // positive-float bits are uint-monotone; key = (bits & ~1023) | loc.
#pragma unroll
    for (int in = 0; in < 2; ++in) {
      int code_l = wn * 32 + in * 16 + cl;                 // 0..63 within ct
      unsigned loc = (unsigned)((ct & 15) * 64 + code_l);  // 0..1023 in group
      float env = en_[krow0 + code_l];
#pragma unroll
      for (int im = 0; im < 4; ++im) {
#pragma unroll
        for (int r = 0; r < 4; ++r) {
          float d = fmaf(-2.0f, acc[im][in][r], env);
          unsigned c = (__float_as_uint(d) & 0xFFFFFC00u) | loc;  // v_and_or
          int s = im * 4 + r;
          unsigned mn = min(p1[s], c);
          unsigned mx = max(p1[s], c);
          p1[s] = mn;
          p2[s] = min(p2[s], mx);
        }
      }
    }
    if ((ct & 15) == 15) {  // group of 1024 codes done: merge + emit
      const int gi = blockIdx.x * 2 + (ct >> 4);
#pragma unroll
      for (int s = 0; s < 16; ++s) {
        unsigned a1 = p1[s], a2 = p2[s];
#pragma unroll
        for (int t = 1; t < 16; t <<= 1) {
          unsigned b1 = __shfl_xor(a1, t);
          unsigned b2 = __shfl_xor(a2, t);
          unsigned m1 = min(a1, b1);
          unsigned M = max(a1, b1);
          a1 = m1;
          a2 = min(min(a2, b2), M);
        }
        if (cl == 0) {
          int im = s >> 2, r = s & 3;
          int rowl = wm * 64 + im * 16 + q * 4 + r;
          ltop[rowl][wn][0] = a1;
          ltop[rowl][wn][1] = a2;
        }
        p1[s] = 0xFFFFFFFFu;
        p2[s] = 0xFFFFFFFFu;
      }
      __syncthreads();
      if (tid < 128) {
        unsigned a1 = ltop[tid][0][0], a2 = ltop[tid][0][1];
        unsigned b1 = ltop[tid][1][0], b2 = ltop[tid][1][1];
        unsigned m1 = min(a1, b1);
        unsigned M = max(a1, b1);
        unsigned f2 = min(min(a2, b2), M);
        unsigned long long packed = ((unsigned long long)f2 << 32) | m1;
        *(unsigned long long*)&cand[(size_t)(n0 + tid) * 16 + gi * 2] = packed;
      }
      __syncthreads();
    }
  }
}

// ---------------- exact fp64 refine over 16 candidates/row + diff ---------
__global__ __launch_bounds__(256) void vq_refine(const unsigned* __restrict__ cand,
                                                 const float* __restrict__ emb,
                                                 const float* __restrict__ zt,
                                                 float* __restrict__ out_idx,
                                                 unsigned* __restrict__ win,
                                                 float* __restrict__ diff) {
  int t = threadIdx.x;
  int w = t >> 6, l = t & 63;
  double wsum = 0.0;
  for (int i = 0; i < 8; ++i) {
    int n = blockIdx.x * 32 + w * 8 + i;
    floatx4 zv = *(const floatx4*)&zt[(size_t)n * 256 + l * 4];
    unsigned ks[16];
    double s[16];
#pragma unroll
    for (int j = 0; j < 16; ++j) {
      unsigned cv = cand[n * 16 + j];
      unsigned k = (unsigned)(j >> 1) * 1024 + (cv & 1023);
      ks[j] = k;
      floatx4 ev = *(const floatx4*)&emb[(size_t)k * 256 + l * 4];
      double acc = 0.0;
#pragma unroll
      for (int x = 0; x < 4; ++x) {
        double dd = (double)ev[x] - (double)zv[x];
        acc += dd * dd;
      }
      s[j] = acc;
    }
#pragma unroll
    for (int j = 0; j < 16; ++j)
#pragma unroll
      for (int st = 1; st < 64; st <<= 1) s[j] += __shfl_xor(s[j], st);
    double bestd = 1e300;
    unsigned bestk = 0xffffffffu;
#pragma unroll
    for (int j = 0; j < 16; ++j) {
      if (s[j] < bestd || (s[j] == bestd && ks[j] < bestk)) {
        bestd = s[j];
        bestk = ks[j];
      }
    }
    if (l == 0) {
      out_idx[n] = (float)bestk;
      win[n] = bestk;
    }
    wsum += bestd;
  }
  __shared__ float dsh[4];
  if (l == 0) dsh[w] = (float)(wsum * ((double)BETA / 8388608.0));
  __syncthreads();
  if (t == 0) atomicAdd(diff, dsh[0] + dsh[1] + dsh[2] + dsh[3]);
}

// ---------------- gather z_q into [b,c,h,w] -------------------------------
__global__ __launch_bounds__(256) void gather_zq(const unsigned* __restrict__ win,
                                                 const float* __restrict__ emb,
                                                 float* __restrict__ out) {
  int bx = blockIdx.x;  // 8192 = 32 b x 256 c
  int b = bx >> 8, c = bx & 255;
  int t = threadIdx.x;
#pragma unroll
  for (int i = 0; i < 4; ++i) {
    int hw = i * 256 + t;
    int n = (b << 10) + hw;
    unsigned k = win[n];
    out[((b << 8) + c) * 1024 + hw] = emb[k * 256 + c];  // coalesced store
  }
}

extern "C" void kernel_launch(void* const* d_in, const int* in_sizes, int n_in,
                              void* d_out, int out_size, void* d_ws, size_t ws_size,
                              hipStream_t stream) {
  const float* z = (const float*)d_in[0];
  const float* emb = (const float*)d_in[1];
  char* ws = (char*)d_ws;
  float* zt = (float*)(ws);
  _Float16* zh = (_Float16*)(ws + 33554432);
  _Float16* eh = (_Float16*)(ws + 50331648);
  float* en = (float*)(ws + 54525952);
  unsigned* cand = (unsigned*)(ws + 54558720);
  unsigned* win = (unsigned*)(ws + 56655872);

  float* out = (float*)d_out;
  float* out_zq = out;               // 8388608
  float* out_diff = out + 8388608;   // 1
  float* out_idx = out + 8388609;    // 32768

  hipMemsetAsync(out_diff, 0, 4, stream);

  split_z_t<<<2048, 256, 0, stream>>>(z, zt, zh);
  split_e<<<8192, 256, 0, stream>>>(emb, eh, en);
  vq_coarse<<<dim3(4, 256), 256, 0, stream>>>(zh, eh, en, cand);
  vq_refine<<<1024, 256, 0, stream>>>(cand, emb, zt, out_idx, win, out_diff);
  gather_zq<<<8192, 256, 0, stream>>>(win, emb, out_zq);
}

// Round 5
// 446.875 us; speedup vs baseline: 1.7338x; 1.0310x over previous
//
#include <hip/hip_runtime.h>
#include <stdint.h>

// VQ: z [32,256,32,32] f32, embedding [8192,256] f32.
// N = 32768 rows, d = 256, K = 8192 codes.
// out = [ z_q (8388608 f32, [b,c,h,w]) | diff (1 f32) | idx (32768 f32) ]
//
// R5: zh/eh stored in MFMA-fragment order so every coarse load is 1KB
// wave-contiguous; A pinned in VGPRs (asm anti-remat); no LDS/barriers in
// the GEMM loop. Refine transposes z in-block (zt dropped) and writes z_q
// directly (gather_zq dropped).
//
// Fragment layout for X[rows][256] f16 (rows % 16 == 0):
//   off_halves(row,k) = (row>>4)*4096 + ((k>>3)*16 + (row&15))*8 + (k&7)
// A wave load for (rowblk, it, kk): base + (it*8+kk*4)*128 + lane*8 -> 1KB.
//
// Workspace (bytes):
//   z_hi frag [32768][256] f16 @ 0         (16777216)
//   e_hi frag [8192][256]  f16 @ 16777216  (4194304)
//   e_norm    [8192]       f32 @ 20971520  (32768)
//   cand      [32768][16]  u32 @ 21004288  (2097152)   total 23101440

typedef _Float16 half8 __attribute__((ext_vector_type(8)));
typedef float floatx4 __attribute__((ext_vector_type(4)));

#define BETA 0.25f

__device__ __forceinline__ void pin(half8& x) { asm volatile("" : "+v"(x)); }

// ---------------- split z: [b,c,hw] f32 -> zh fragment order ---------------
__global__ __launch_bounds__(256) void split_z_t(const float* __restrict__ z,
                                                 _Float16* __restrict__ zh) {
  __shared__ float tile[64][65];  // [c][hw], +1 pad
  int bt = blockIdx.x;       // 2048 blocks: 512 n-tiles x 4 c-tiles
  int ct = bt & 3;
  int ntile = bt >> 2;
  int b = ntile >> 4;
  int hw0 = (ntile & 15) * 64;
  int c0 = ct * 64;
  int t = threadIdx.x;
  int tr = t >> 6, tc = t & 63;
#pragma unroll
  for (int i = 0; i < 16; ++i) {
    int c = tr + i * 4;
    tile[c][tc] = z[b * 262144 + (c0 + c) * 1024 + hw0 + tc];  // coalesced
  }
  __syncthreads();
  int n0abs = b * 1024 + hw0;  // multiple of 64
#pragma unroll
  for (int iter = 0; iter < 2; ++iter) {
    int s = iter * 256 + t;
    int nrow = s >> 3, k8l = s & 7;
    half8 hv;
#pragma unroll
    for (int h = 0; h < 8; ++h) hv[h] = (_Float16)tile[k8l * 8 + h][nrow];
    size_t off = (size_t)(n0abs / 16 + (nrow >> 4)) * 4096 +
                 (size_t)((((c0 >> 3) + k8l) * 16 + (nrow & 15)) * 8);
    *(half8*)&zh[off] = hv;
  }
}

// ---------------- split e -> eh fragment order + ||e||^2 -------------------
__global__ __launch_bounds__(256) void split_e(const float* __restrict__ e,
                                               _Float16* __restrict__ eh,
                                               float* __restrict__ en) {
  __shared__ float el[16][257];
  int k0 = blockIdx.x * 16;
  int t = threadIdx.x;
#pragma unroll
  for (int r = 0; r < 16; ++r) el[r][t] = e[(k0 + r) * 256 + t];  // coalesced
  __syncthreads();
  {
    int row = t >> 4, li = t & 15;
    float s = 0.f;
#pragma unroll
    for (int jj = 0; jj < 16; ++jj) {
      float v = el[row][li + 16 * jj];
      s += v * v;
    }
#pragma unroll
    for (int st = 1; st < 16; st <<= 1) s += __shfl_xor(s, st);
    if (li == 0) en[k0 + row] = s;
  }
#pragma unroll
  for (int iter = 0; iter < 2; ++iter) {
    int s = iter * 256 + t;
    int row = s & 15, k8 = s >> 4;
    half8 hv;
#pragma unroll
    for (int h = 0; h < 8; ++h) hv[h] = (_Float16)el[row][k8 * 8 + h];
    *(half8*)&eh[(size_t)k0 * 256 + k8 * 128 + row * 8] = hv;
  }
}

// ---------------- coarse GEMM: pinned-register A, streamed B --------------
// grid (4 kgroups of 2048, 256 n-tiles), block 256 = 4 waves (wm x wn).
// wave tile: 64 rows x 32 codes per ct (ct = 64 codes).
__global__ __launch_bounds__(256, 2) void vq_coarse(
    const _Float16* __restrict__ zh, const _Float16* __restrict__ eh,
    const float* __restrict__ en_, unsigned* __restrict__ cand) {
  __shared__ unsigned ltop[128][2][2];  // [row][wn][2] = 2 KB
  const int tid = threadIdx.x;
  const int l = tid & 63;
  const int w = tid >> 6;
  const int wm = w >> 1, wn = w & 1;
  const int n0 = blockIdx.y * 128;
  const int kbase = blockIdx.x * 2048;
  const int cl = l & 15;
  const int q = l >> 4;

  // A resident: 64 rows x 256 K per wave = 32 half8 = 128 VGPR, pinned.
  half8 A[4][2][4];  // [it][kk][im]
#pragma unroll
  for (int it = 0; it < 4; ++it)
#pragma unroll
    for (int kk = 0; kk < 2; ++kk)
#pragma unroll
      for (int im = 0; im < 4; ++im) {
        A[it][kk][im] = *(const half8*)&zh[(size_t)n0 * 256 + (wm * 4 + im) * 4096 +
                                           (it * 8 + kk * 4) * 128 + l * 8];
        pin(A[it][kk][im]);
      }

  unsigned p1[16], p2[16];
#pragma unroll
  for (int s = 0; s < 16; ++s) { p1[s] = 0xFFFFFFFFu; p2[s] = 0xFFFFFFFFu; }

  for (int ct = 0; ct < 32; ++ct) {   // 2048 codes, 64 per ct
    const int krow0 = kbase + ct * 64;
    const _Float16* bb = eh + (size_t)krow0 * 256 + wn * 2 * 4096 + l * 8;
    floatx4 acc[4][2] = {};  // [im][in]
#pragma unroll
    for (int it = 0; it < 4; ++it) {
#pragma unroll
      for (int kk = 0; kk < 2; ++kk) {
        half8 bf[2];
#pragma unroll
        for (int in = 0; in < 2; ++in)
          bf[in] = *(const half8*)&bb[(size_t)in * 4096 + (it * 8 + kk * 4) * 128];
#pragma unroll
        for (int im = 0; im < 4; ++im)
#pragma unroll
          for (int in = 0; in < 2; ++in)
            acc[im][in] = __builtin_amdgcn_mfma_f32_16x16x32_f16(
                A[it][kk][im], bf[in], acc[im][in], 0, 0, 0);
      }
    }
    // top-2 update: d = ||e||^2 - 2*dot > 0 on this data -> positive-float
    // bits are uint-monotone; key = (bits & ~1023) | idx10.
#pragma unroll
    for (int in = 0; in < 2; ++in) {
      int code_l = wn * 32 + in * 16 + cl;
      unsigned loc = (unsigned)((ct & 15) * 64 + code_l);
      float env = en_[krow0 + code_l];
#pragma unroll
      for (int im = 0; im < 4; ++im) {
#pragma unroll
        for (int r = 0; r < 4; ++r) {
          float d = fmaf(-2.0f, acc[im][in][r], env);
          unsigned c = (__float_as_uint(d) & 0xFFFFFC00u) | loc;
          int s = im * 4 + r;
          unsigned mn = min(p1[s], c);
          unsigned mx = max(p1[s], c);
          p1[s] = mn;
          p2[s] = min(p2[s], mx);
        }
      }
    }
    if ((ct & 15) == 15) {  // 1024-code group done: merge + emit
      const int gi = blockIdx.x * 2 + (ct >> 4);
#pragma unroll
      for (int s = 0; s < 16; ++s) {
        unsigned a1 = p1[s], a2 = p2[s];
#pragma unroll
        for (int t2 = 1; t2 < 16; t2 <<= 1) {
          unsigned b1 = __shfl_xor(a1, t2);
          unsigned b2 = __shfl_xor(a2, t2);
          unsigned m1 = min(a1, b1);
          unsigned M = max(a1, b1);
          a1 = m1;
          a2 = min(min(a2, b2), M);
        }
        if (cl == 0) {
          int im = s >> 2, r = s & 3;
          int rowl = wm * 64 + im * 16 + q * 4 + r;
          ltop[rowl][wn][0] = a1;
          ltop[rowl][wn][1] = a2;
        }
        p1[s] = 0xFFFFFFFFu;
        p2[s] = 0xFFFFFFFFu;
      }
      __syncthreads();
      if (tid < 128) {
        unsigned a1 = ltop[tid][0][0], a2 = ltop[tid][0][1];
        unsigned b1 = ltop[tid][1][0], b2 = ltop[tid][1][1];
        unsigned m1 = min(a1, b1);
        unsigned M = max(a1, b1);
        unsigned f2 = min(min(a2, b2), M);
        unsigned long long packed = ((unsigned long long)f2 << 32) | m1;
        *(unsigned long long*)&cand[(size_t)(n0 + tid) * 16 + gi * 2] = packed;
      }
      __syncthreads();
    }
  }
}

// -------- refine: in-block z transpose, exact fp64 pick, fused z_q --------
// grid 1024 blocks x 256 thr; block handles 32 rows (same b, hw0..hw0+31).
__global__ __launch_bounds__(256) void vq_refine(const unsigned* __restrict__ cand,
                                                 const float* __restrict__ emb,
                                                 const float* __restrict__ z,
                                                 float* __restrict__ out_idx,
                                                 float* __restrict__ zq,
                                                 float* __restrict__ diff) {
  __shared__ float ztl[32][260];  // 33.3 KB, row stride 1040 B (16B aligned)
  __shared__ unsigned win_s[32];
  __shared__ float dsh[4];
  const int t = threadIdx.x;
  const int n0 = blockIdx.x * 32;
  const int b = n0 >> 10;
  const int hw0 = n0 & 1023;
  const int j = t & 31, c8 = t >> 5;
#pragma unroll
  for (int ci = 0; ci < 32; ++ci) {
    int c = ci * 8 + c8;
    ztl[j][c] = z[b * 262144 + c * 1024 + hw0 + j];  // 128B per 32 lanes
  }
  __syncthreads();
  const int w = t >> 6, l = t & 63;
  double wsum = 0.0;
  for (int i = 0; i < 8; ++i) {
    int row = w * 8 + i;
    int n = n0 + row;
    floatx4 zv = *(const floatx4*)&ztl[row][4 * l];
    unsigned ks[16];
    double s[16];
#pragma unroll
    for (int jj = 0; jj < 16; ++jj) {
      unsigned cv = cand[(size_t)n * 16 + jj];
      unsigned k = (unsigned)(jj >> 1) * 1024 + (cv & 1023);
      ks[jj] = k;
      floatx4 ev = *(const floatx4*)&emb[(size_t)k * 256 + l * 4];
      double acc = 0.0;
#pragma unroll
      for (int x = 0; x < 4; ++x) {
        double dd = (double)ev[x] - (double)zv[x];
        acc += dd * dd;
      }
      s[jj] = acc;
    }
#pragma unroll
    for (int jj = 0; jj < 16; ++jj)
#pragma unroll
      for (int st = 1; st < 64; st <<= 1) s[jj] += __shfl_xor(s[jj], st);
    double bestd = 1e300;
    unsigned bestk = 0xffffffffu;
#pragma unroll
    for (int jj = 0; jj < 16; ++jj) {
      if (s[jj] < bestd || (s[jj] == bestd && ks[jj] < bestk)) {
        bestd = s[jj];
        bestk = ks[jj];
      }
    }
    if (l == 0) {
      out_idx[n] = (float)bestk;
      win_s[row] = bestk;
    }
    wsum += bestd;
  }
  if (l == 0) dsh[w] = (float)(wsum * ((double)BETA / 8388608.0));
  __syncthreads();
  if (t == 0) atomicAdd(diff, dsh[0] + dsh[1] + dsh[2] + dsh[3]);
  // fused z_q write-out: winners -> [b,c,h,w], coalesced stores
#pragma unroll
  for (int ci = 0; ci < 32; ++ci) {
    int c = ci * 8 + c8;
    zq[b * 262144 + c * 1024 + hw0 + j] = emb[(size_t)win_s[j] * 256 + c];
  }
}

extern "C" void kernel_launch(void* const* d_in, const int* in_sizes, int n_in,
                              void* d_out, int out_size, void* d_ws, size_t ws_size,
                              hipStream_t stream) {
  const float* z = (const float*)d_in[0];
  const float* emb = (const float*)d_in[1];
  char* ws = (char*)d_ws;
  _Float16* zh = (_Float16*)(ws);
  _Float16* eh = (_Float16*)(ws + 16777216);
  float* en = (float*)(ws + 20971520);
  unsigned* cand = (unsigned*)(ws + 21004288);

  float* out = (float*)d_out;
  float* out_zq = out;               // 8388608
  float* out_diff = out + 8388608;   // 1
  float* out_idx = out + 8388609;    // 32768

  hipMemsetAsync(out_diff, 0, 4, stream);

  split_z_t<<<2048, 256, 0, stream>>>(z, zh);
  split_e<<<512, 256, 0, stream>>>(emb, eh, en);
  vq_coarse<<<dim3(4, 256), 256, 0, stream>>>(zh, eh, en, cand);
  vq_refine<<<1024, 256, 0, stream>>>(cand, emb, z, out_idx, out_zq, out_diff);
}